// Round 1
// baseline (288.075 us; speedup 1.0000x reference)
//
#include <hip/hip_runtime.h>
#include <math.h>

// ---- problem constants ----
#define TI    8
#define DI    8
#define TO    16
#define DOUT  8
#define CH    128      // TO*DOUT
#define HH    64
#define WW    64
#define HO    62
#define WO    62
#define KTOT  72       // DI*3*3
#define PX    31       // pixels per workgroup (half an output row)

// ---- LDS layout (floats) ----
#define US_P  1032     // uhat pixel stride (1024 + 8 pad -> breaks bank aliasing)
#define XROW  36       // xpatch row stride (33 cols + pad, 16B aligned)
#define NROWS (TI*DI*3)
#define CV_P  132      // c/v buffer pixel stride (128 + 4 pad)

#define UHAT_OFF 0
#define XP_OFF   (PX*US_P)                   // 31992 floats
#define LDS_FLOATS (XP_OFF + NROWS*XROW)     // 31992 + 6912 = 38904 floats = 155616 B

extern __shared__ float lds[];

__global__ __launch_bounds__(256, 1)
void caps_fused(const float* __restrict__ x, const float* __restrict__ w,
                const float* __restrict__ cbias, const float* __restrict__ rbias,
                float* __restrict__ out)
{
    const int tid = threadIdx.x;
    const int wg  = blockIdx.x;
    const int n   = wg / (HO * 2);
    const int rem = wg % (HO * 2);
    const int ho  = rem >> 1;
    const int wo0 = (rem & 1) * PX;

    float* uhat = lds + UHAT_OFF;
    float* xp   = lds + XP_OFF;
    float* cv   = lds + XP_OFF;   // aliases xpatch; only used after conv is done

    // ---------------- stage x patch: rows (ti,di,kh) x cols 0..32 ----------------
    {
        const float* xbase = x + (size_t)n * (TI * DI * HH * WW);
        for (int i = tid; i < NROWS * 33; i += 256) {
            int row  = i / 33;            // (ti*DI+di)*3 + kh
            int col  = i % 33;
            int kh   = row % 3;
            int tidi = row / 3;           // ti*DI + di
            xp[row * XROW + col] =
                xbase[(size_t)tidi * (HH * WW) + (ho + kh) * WW + wo0 + col];
        }
        for (int i = tid; i < NROWS * 3; i += 256) {   // zero the pad cols 33..35
            int row = i / 3; int c = 33 + i % 3;
            xp[row * XROW + c] = 0.f;
        }
    }
    __syncthreads();

    // ---------------- grouped conv -> uhat in LDS ----------------
    // thread = (channel, pixel-half). Weights in regs, x rows broadcast from LDS.
    const int ch     = tid & 127;
    const int grp    = tid >> 7;          // 0: px 0..15, 1: px 16..30
    const int pxbase = grp * 16;
    const int npx    = grp ? 15 : 16;

    for (int ti = 0; ti < TI; ++ti) {
        float wreg[KTOT];
        {
            const float4* wp = (const float4*)(w + (size_t)(ti * CH + ch) * KTOT);
            #pragma unroll
            for (int q = 0; q < 18; ++q) {
                float4 v4 = wp[q];
                wreg[4*q+0] = v4.x; wreg[4*q+1] = v4.y;
                wreg[4*q+2] = v4.z; wreg[4*q+3] = v4.w;
            }
        }
        float acc[16];
        #pragma unroll
        for (int j = 0; j < 16; ++j) acc[j] = 0.f;

        #pragma unroll
        for (int di = 0; di < DI; ++di) {
            #pragma unroll
            for (int kh = 0; kh < 3; ++kh) {
                const float4* xr4 =
                    (const float4*)(xp + ((ti * DI + di) * 3 + kh) * XROW + pxbase);
                float xr[20];
                #pragma unroll
                for (int q = 0; q < 5; ++q) {
                    float4 v4 = xr4[q];
                    xr[4*q+0] = v4.x; xr[4*q+1] = v4.y;
                    xr[4*q+2] = v4.z; xr[4*q+3] = v4.w;
                }
                #pragma unroll
                for (int kw = 0; kw < 3; ++kw) {
                    float wv = wreg[di * 9 + kh * 3 + kw];
                    #pragma unroll
                    for (int j = 0; j < 16; ++j)
                        acc[j] = fmaf(wv, xr[j + kw], acc[j]);
                }
            }
        }
        float bv = cbias[ti * CH + ch];
        for (int j = 0; j < npx; ++j)
            uhat[(size_t)(pxbase + j) * US_P + ti * CH + ch] = acc[j] + bv;
    }
    __syncthreads();

    // ---------------- dynamic routing (3 rounds) ----------------
    // 8 threads per pixel: thread role = ti (softmax/agreement) or do (s/squash).
    const bool act = (tid < PX * 8);
    const int p = tid >> 3;
    const int t = tid & 7;

    float breg[TO];
    #pragma unroll
    for (int o = 0; o < TO; ++o) breg[o] = 0.f;

    float rb[TO];
    if (act) {
        #pragma unroll
        for (int o = 0; o < TO; ++o) rb[o] = rbias[o * DOUT + t];
    }

    float v[TO];

    for (int r = 0; r < 3; ++r) {
        // phase C: c = softmax_to(b) for ti = t  -> cv[p][t*16+o]
        if (act) {
            float m = breg[0];
            #pragma unroll
            for (int o = 1; o < TO; ++o) m = fmaxf(m, breg[o]);
            float ssum = 0.f; float e[TO];
            #pragma unroll
            for (int o = 0; o < TO; ++o) { e[o] = __expf(breg[o] - m); ssum += e[o]; }
            float inv = 1.f / ssum;
            #pragma unroll
            for (int o = 0; o < TO; ++o) cv[p * CV_P + t * TO + o] = e[o] * inv;
        }
        __syncthreads();

        // phase S: s[to] for do = t; then squash over do via 8-lane shfl reduce
        if (act) {
            #pragma unroll
            for (int o = 0; o < TO; ++o) {
                float s = rb[o];
                for (int ti2 = 0; ti2 < TI; ++ti2)
                    s = fmaf(cv[p * CV_P + ti2 * TO + o],
                             uhat[(size_t)p * US_P + ti2 * CH + o * DOUT + t], s);
                v[o] = s;
            }
            #pragma unroll
            for (int o = 0; o < TO; ++o) {
                float n2 = v[o] * v[o];
                n2 += __shfl_xor(n2, 1);
                n2 += __shfl_xor(n2, 2);
                n2 += __shfl_xor(n2, 4);
                float scale = n2 / (1.f + n2) * rsqrtf(n2 + 1e-9f);
                v[o] *= scale;
            }
        }
        __syncthreads();   // all c reads done -> safe to overwrite cv with v

        if (act) {
            #pragma unroll
            for (int o = 0; o < TO; ++o) cv[p * CV_P + o * DOUT + t] = v[o];
        }
        __syncthreads();

        if (r < 2) {
            // phase A: agreement for ti = t: b[to] += sum_do uhat*v
            if (act) {
                #pragma unroll
                for (int o = 0; o < TO; ++o) {
                    float a = 0.f;
                    #pragma unroll
                    for (int d = 0; d < DOUT; ++d)
                        a = fmaf(uhat[(size_t)p * US_P + t * CH + o * DOUT + d],
                                 cv[p * CV_P + o * DOUT + d], a);
                    breg[o] += a;
                }
            }
            __syncthreads();   // protect cv before next round's c writes
        }
    }

    // ---------------- coalesced output write from cv (holds final v) ----------------
    // out[n][c=to*8+do][ho][wo0+p]
    for (int i = tid; i < CH * PX; i += 256) {
        int c  = i / PX;
        int p2 = i % PX;
        out[((size_t)n * CH + c) * (HO * WO) + ho * WO + wo0 + p2] =
            cv[p2 * CV_P + c];
    }
}

extern "C" void kernel_launch(void* const* d_in, const int* in_sizes, int n_in,
                              void* d_out, int out_size, void* d_ws, size_t ws_size,
                              hipStream_t stream) {
    const float* x    = (const float*)d_in[0];
    const float* cw   = (const float*)d_in[1];
    const float* cb   = (const float*)d_in[2];
    const float* rb   = (const float*)d_in[3];
    float* out = (float*)d_out;

    const size_t lds_bytes = (size_t)LDS_FLOATS * sizeof(float);
    hipFuncSetAttribute(reinterpret_cast<const void*>(caps_fused),
                        hipFuncAttributeMaxDynamicSharedMemorySize,
                        (int)lds_bytes);

    const int n_wg = 8 * HO * 2;   // 992
    caps_fused<<<n_wg, 256, lds_bytes, stream>>>(x, cw, cb, rb, out);
}